// Round 12
// baseline (312.914 us; speedup 1.0000x reference)
//
#include <hip/hip_runtime.h>
#include <hip/hip_bf16.h>

// Problem: B=8, S=1024, D=256, H=8, HD=32
// Pipeline (3 kernels):
//   prep:      q,Wq,Wk,Wv,Wo f32 -> bf16; kv_mask -> additive f32; zero sync cnt
//   qkv_gemm:  z=0: qh=(q@Wq^T+bq)*SCL, z=1: kh=q@Wk^T+bk, z=2: vt=Wv@q^T+bv (V^T)
//   attn:      flash attention, block=(b, 32-q-tile), wave=head w/ 2 q-subtiles.
//              NEW (R12): per-batch rendezvous every 2 k-tiles (device-scope
//              atomic counter + spin in thread 0). Keeps the 32 sibling blocks
//              of a batch k-phase-aligned so K/V tiles fetched by the first
//              toucher are L2-hits for the other 31 (drift previously caused
//              ~256 MB of K/V HBM re-fetch = the dominant cost term).
//              No online max; raw lgkm-only barriers; 2-deep bias prefetch.
//              Fused LayerNorm + @Wo^T+bo -> d_out (f32).
//
// Workspace: q_bf(4M) qh(4M@4M) kh(4M@8M) vt(4M@12M) w_bf(512K@16M)
//            mskf(32K@17M) cnt(32B @17M+32K)

static constexpr int SEQ = 1024;
static constexpr float SCL  = 0.17677669529663687f;  // 1/sqrt(32)
static constexpr float NEGV = -1000000000.0f;

typedef __attribute__((ext_vector_type(8))) __bf16 bf8v;
typedef __attribute__((ext_vector_type(4))) float  f4v;

__device__ __forceinline__ f4v mfma16(bf8v a, bf8v b, f4v c) {
  return __builtin_amdgcn_mfma_f32_16x16x32_bf16(a, b, c, 0, 0, 0);
}
__device__ __forceinline__ unsigned short bfbits(float f) {
  __hip_bfloat16 hbf = __float2bfloat16(f);
  unsigned short u; __builtin_memcpy(&u, &hbf, 2); return u;
}
__device__ __forceinline__ float bf2f(unsigned short u) {
  unsigned x = ((unsigned)u) << 16; float f; __builtin_memcpy(&f, &x, 4); return f;
}
// Barrier that does NOT drain outstanding global (vmcnt) loads.
__device__ __forceinline__ void lds_barrier() {
  __builtin_amdgcn_sched_barrier(0);
  asm volatile("s_waitcnt lgkmcnt(0)" ::: "memory");
  __builtin_amdgcn_s_barrier();
  __builtin_amdgcn_sched_barrier(0);
}

// ---------------------------------------------------------------- prep
__global__ __launch_bounds__(256) void prep_kernel(
    const float* __restrict__ q, const float* __restrict__ Wq,
    const float* __restrict__ Wk, const float* __restrict__ Wv,
    const float* __restrict__ Wo, const int* __restrict__ km,
    __hip_bfloat16* __restrict__ q_bf, __hip_bfloat16* __restrict__ w_bf,
    float* __restrict__ mskf, unsigned* __restrict__ cnt)
{
  const int NQ4 = (8192 * 256) / 4;
  const int NW4 = 65536 / 4;
  int t = threadIdx.x;

  if (blockIdx.x == 2304) {
    if (t < 8) cnt[t] = 0u;   // rendezvous counters (fresh each launch/replay)
    __shared__ int isbool;
    if (t == 0) isbool = 0;
    __syncthreads();
    const unsigned* u = (const unsigned*)km;
    int any = 0;
    for (int i = t; i < 2048; i += 256)
      if (u[i] & ~1u) any = 1;
    if (any) isbool = 1;   // benign race
    __syncthreads();
    const unsigned char* b8 = (const unsigned char*)km;
    for (int i = t; i < 8192; i += 256) {
      int mv = isbool ? (int)b8[i] : km[i];
      mskf[i] = mv ? 0.f : NEGV;
    }
    return;
  }

  int i = blockIdx.x * 256 + t;
  const float4* src; __hip_bfloat16* dst;
  if (i < NQ4) {
    src = (const float4*)q + i;
    dst = q_bf + (long)i * 4;
  } else {
    int j = i - NQ4; int w = j >> 14; int o4 = j & (NW4 - 1);
    const float* sp = (w == 0) ? Wq : (w == 1) ? Wk : (w == 2) ? Wv : Wo;
    src = (const float4*)sp + o4;
    dst = w_bf + w * 65536 + o4 * 4;
  }
  float4 v = *src;
  ushort4 pk;
  pk.x = bfbits(v.x); pk.y = bfbits(v.y); pk.z = bfbits(v.z); pk.w = bfbits(v.w);
  *reinterpret_cast<ushort4*>(dst) = pk;
}

// ------------------------------------------------- fused QKV GEMM (K=256)
__global__ __launch_bounds__(256) void qkv_gemm(
    const __hip_bfloat16* __restrict__ q_bf, const __hip_bfloat16* __restrict__ w_bf,
    const float* __restrict__ bq, const float* __restrict__ bk,
    const float* __restrict__ bv,
    __hip_bfloat16* __restrict__ qh, __hip_bfloat16* __restrict__ kh,
    __hip_bfloat16* __restrict__ vt)
{
  int z = blockIdx.z;
  int w = threadIdx.x >> 6;
  int l = threadIdx.x & 63, lr = l & 15, lg = l >> 4;

  const __hip_bfloat16 *A, *Bm; const float* bias; __hip_bfloat16* out;
  long ldOut; int m0, n0;
  if (z < 2) {
    A = q_bf; Bm = w_bf + z * 65536; bias = z ? bk : bq; out = z ? kh : qh;
    ldOut = 256;
    m0 = blockIdx.x * 64; n0 = blockIdx.y * 128 + w * 32;
  } else {
    A = w_bf + 2 * 65536; Bm = q_bf; bias = bv; out = vt; ldOut = 8192;
    int bid = blockIdx.y * 128 + blockIdx.x;
    m0 = (bid >> 6) * 64; n0 = (bid & 63) * 128 + w * 32;
  }

  f4v acc[4][2];
#pragma unroll
  for (int mt = 0; mt < 4; ++mt)
#pragma unroll
    for (int nt = 0; nt < 2; ++nt) acc[mt][nt] = f4v{0.f, 0.f, 0.f, 0.f};

  const __hip_bfloat16* Ab = A  + (long)(m0 + lr) * 256 + lg * 8;
  const __hip_bfloat16* Bb = Bm + (long)(n0 + lr) * 256 + lg * 8;
#pragma unroll
  for (int k0 = 0; k0 < 256; k0 += 32) {
    bf8v af[4], bfr[2];
#pragma unroll
    for (int mt = 0; mt < 4; ++mt)
      af[mt] = *reinterpret_cast<const bf8v*>(Ab + (long)mt * 16 * 256 + k0);
#pragma unroll
    for (int nt = 0; nt < 2; ++nt)
      bfr[nt] = *reinterpret_cast<const bf8v*>(Bb + (long)nt * 16 * 256 + k0);
#pragma unroll
    for (int mt = 0; mt < 4; ++mt)
#pragma unroll
      for (int nt = 0; nt < 2; ++nt)
        acc[mt][nt] = mfma16(af[mt], bfr[nt], acc[mt][nt]);
  }

#pragma unroll
  for (int mt = 0; mt < 4; ++mt) {
    int mrow = m0 + mt * 16 + lg * 4;
#pragma unroll
    for (int nt = 0; nt < 2; ++nt) {
      int ncol = n0 + nt * 16 + lr;
#pragma unroll
      for (int r = 0; r < 4; ++r) {
        float v = acc[mt][nt][r] + ((z == 2) ? bias[mrow + r] : bias[ncol]);
        if (z == 0) v *= SCL;   // fold 1/sqrt(HD) into Q projection
        out[(long)(mrow + r) * ldOut + ncol] = __float2bfloat16(v);
      }
    }
  }
}

// ---------------------------------------------------------------- attention
// grid = 256 (wgid = qt*8 + b), block = 512 (8 waves; wave = head, 32 q-rows
// as 2 subtiles). KT=32, raw barrier per tile, per-batch rendezvous per 2 tiles.
__global__ __launch_bounds__(512, 2) void attn_kernel(
    const __hip_bfloat16* __restrict__ qh, const __hip_bfloat16* __restrict__ kh,
    const __hip_bfloat16* __restrict__ vt, const float* __restrict__ bias,
    const float* __restrict__ mskf, const __hip_bfloat16* __restrict__ wob,
    const float* __restrict__ gamma, const float* __restrict__ beta,
    const float* __restrict__ bo, unsigned* __restrict__ cnt,
    float* __restrict__ outp)
{
  // loop:   bsm 2 x [32 q][8h x 36 + 4 pad = 292] bf16 = 37376 B
  //         psm [8w][16 q][40 k] bf16 = 10240 B @37376 ; msk 1024 f32 @47616
  // epilogue: osm f32 [32][264] = 33792 B @0 ; ansm bf16 [32][264] = 16896 B @33792
  __shared__ __align__(16) char smem[51712];
  __hip_bfloat16* bsm = (__hip_bfloat16*)smem;
  __hip_bfloat16* psm = (__hip_bfloat16*)(smem + 37376);
  float* msk = (float*)(smem + 47616);
  float* osm = (float*)smem;
  __hip_bfloat16* ansm = (__hip_bfloat16*)(smem + 33792);

  int bb = blockIdx.x & 7;           // XCD-affinity: batch -> XCD
  int qt = blockIdx.x >> 3;          // 0..31
  int h  = threadIdx.x >> 6;
  int l  = threadIdx.x & 63, lr = l & 15, lg = l >> 4;
  int q0 = qt * 32;
  long bS = (long)bb * SEQ;
  int t = threadIdx.x;
  // staging map: 32 rows x 16 threads; thread -> (q-row sq, k-quad kp, h-half hh)
  int sq = t >> 4, kp = (t >> 1) & 7, hh = t & 1;

  for (int i = t; i < 1024; i += 512) msk[i] = mskf[bS + i];

  bf8v qf[2];
#pragma unroll
  for (int qs = 0; qs < 2; ++qs)
    qf[qs] = *reinterpret_cast<const bf8v*>(
        qh + (bS + q0 + qs * 16 + lr) * 256 + h * 32 + lg * 8);

  f4v o[2][2];
  float lsum[2] = {0.f, 0.f};
#pragma unroll
  for (int qs = 0; qs < 2; ++qs)
#pragma unroll
    for (int nt = 0; nt < 2; ++nt) o[qs][nt] = f4v{0.f, 0.f, 0.f, 0.f};

  const float* bgb = bias + (bS + q0 + sq) * 8192L + 4 * hh;

  auto loadBias = [&](int tile, float4 (&br)[4]) {
    int kb = tile * 32;
#pragma unroll
    for (int kk = 0; kk < 4; ++kk)
      br[kk] = *reinterpret_cast<const float4*>(bgb + (long)(kb + 4 * kp + kk) * 8);
  };
  // (bias + mask) -> bf16 packed along k, layout [q][h][k]
  auto cvtWrite = [&](int buf, const float4 (&br)[4], int tile) {
    int kb = tile * 32;
    float mk[4];
#pragma unroll
    for (int kk = 0; kk < 4; ++kk) mk[kk] = msk[kb + 4 * kp + kk];
    __hip_bfloat16* bp = bsm + buf * 9344 + sq * 292 + 4 * kp;
    float w_[4][4] = {{br[0].x, br[0].y, br[0].z, br[0].w},
                      {br[1].x, br[1].y, br[1].z, br[1].w},
                      {br[2].x, br[2].y, br[2].z, br[2].w},
                      {br[3].x, br[3].y, br[3].z, br[3].w}};
#pragma unroll
    for (int i = 0; i < 4; ++i) {
      ushort4 hb;
      hb.x = bfbits(w_[0][i] + mk[0]); hb.y = bfbits(w_[1][i] + mk[1]);
      hb.z = bfbits(w_[2][i] + mk[2]); hb.w = bfbits(w_[3][i] + mk[3]);
      *reinterpret_cast<ushort4*>(bp + (4 * hh + i) * 36) = hb;
    }
  };
  auto loadKV = [&](int tile, bf8v (&kf)[2], bf8v (&vf)[2]) {
    int kbase = tile * 32;
#pragma unroll
    for (int nt = 0; nt < 2; ++nt)
      kf[nt] = *reinterpret_cast<const bf8v*>(
          kh + (bS + kbase + nt * 16 + lr) * 256 + h * 32 + lg * 8);
#pragma unroll
    for (int n2 = 0; n2 < 2; ++n2)
      vf[n2] = *reinterpret_cast<const bf8v*>(
          vt + (long)(h * 32 + n2 * 16 + lr) * 8192 + bS + kbase + lg * 8);
  };

  auto compute = [&](int kt, const bf8v (&kf)[2], const bf8v (&vf)[2]) {
    const __hip_bfloat16* bbp = bsm + (kt & 1) * 9344;
#pragma unroll
    for (int qs = 0; qs < 2; ++qs) {
      f4v z4 = f4v{0.f, 0.f, 0.f, 0.f};
      f4v s0 = mfma16(kf[0], qf[qs], z4);   // lane q = lr, k = 4lg+j
      f4v s1 = mfma16(kf[1], qf[qs], z4);   // k = 16 + 4lg+j

      const __hip_bfloat16* bp = bbp + (qs * 16 + lr) * 292 + h * 36;
      ushort4 b0 = *reinterpret_cast<const ushort4*>(bp + lg * 4);
      ushort4 b1 = *reinterpret_cast<const ushort4*>(bp + 16 + lg * 4);

      float p[8];
      p[0] = __expf(s0[0] + bf2f(b0.x)); p[1] = __expf(s0[1] + bf2f(b0.y));
      p[2] = __expf(s0[2] + bf2f(b0.z)); p[3] = __expf(s0[3] + bf2f(b0.w));
      p[4] = __expf(s1[0] + bf2f(b1.x)); p[5] = __expf(s1[1] + bf2f(b1.y));
      p[6] = __expf(s1[2] + bf2f(b1.z)); p[7] = __expf(s1[3] + bf2f(b1.w));
      lsum[qs] += ((p[0] + p[1]) + (p[2] + p[3])) + ((p[4] + p[5]) + (p[6] + p[7]));

      __hip_bfloat16* pw = psm + h * 640 + lr * 40;
      ushort4 pk0, pk1;
      pk0.x = bfbits(p[0]); pk0.y = bfbits(p[1]); pk0.z = bfbits(p[2]); pk0.w = bfbits(p[3]);
      pk1.x = bfbits(p[4]); pk1.y = bfbits(p[5]); pk1.z = bfbits(p[6]); pk1.w = bfbits(p[7]);
      *reinterpret_cast<ushort4*>(pw + 4 * lg)      = pk0;
      *reinterpret_cast<ushort4*>(pw + 16 + 4 * lg) = pk1;

      bf8v pa = *reinterpret_cast<const bf8v*>(psm + h * 640 + lr * 40 + lg * 8);
      o[qs][0] = mfma16(pa, vf[0], o[qs][0]);
      o[qs][1] = mfma16(pa, vf[1], o[qs][1]);
    }
  };

  // per-batch rendezvous: re-align the 32 sibling blocks so K/V tiles are
  // L2-shared. Spin only in thread 0 (its vmcnt drain affects wave 0 only);
  // other waves just park at the raw s_barrier (prefetches stay in flight).
  auto rendezvous = [&](int phase) {
    if (t == 0) {
      __hip_atomic_fetch_add(cnt + bb, 1u, __ATOMIC_ACQ_REL,
                             __HIP_MEMORY_SCOPE_AGENT);
      unsigned tgt = 32u * (unsigned)(phase + 1);
      while (__hip_atomic_load(cnt + bb, __ATOMIC_ACQUIRE,
                               __HIP_MEMORY_SCOPE_AGENT) < tgt)
        __builtin_amdgcn_s_sleep(2);
    }
    __builtin_amdgcn_sched_barrier(0);
    __builtin_amdgcn_s_barrier();
    __builtin_amdgcn_sched_barrier(0);
  };

  float4 brA[4], brB[4];
  bf8v kfA[2], vfA[2], kfB[2], vfB[2];

  loadBias(0, brA);
  loadBias(1, brB);
  loadKV(0, kfA, vfA);
  lds_barrier();              // msk visible; prefetches stay in flight
  cvtWrite(0, brA, 0);        // one-time wait on brA
  lds_barrier();

  for (int m = 0; m < 16; ++m) {
    rendezvous(m);
    { int kt = 2 * m;                       // compute even tile from bsm buf0
      if (kt + 2 < 32) loadBias(kt + 2, brA);
      loadKV(kt + 1, kfB, vfB);
      compute(kt, kfA, vfA);
      cvtWrite(1, brB, kt + 1);
      lds_barrier(); }
    { int kt = 2 * m + 1;                   // compute odd tile from bsm buf1
      if (kt + 2 < 32) { loadBias(kt + 2, brB); loadKV(kt + 1, kfA, vfA); }
      compute(kt, kfB, vfB);
      if (kt + 1 < 32) cvtWrite(0, brA, kt + 1);
      lds_barrier(); }
  }

  // ---- epilogue: lsum reduce, stage normalized O, LayerNorm, out-projection ----
  float rinv[2];
#pragma unroll
  for (int qs = 0; qs < 2; ++qs) {
    float s = lsum[qs];
    s += __shfl_xor(s, 16);
    s += __shfl_xor(s, 32);
    rinv[qs] = 1.f / s;
  }

  __syncthreads();   // all waves done with bsm/psm before osm aliases them
#pragma unroll
  for (int qs = 0; qs < 2; ++qs)
#pragma unroll
    for (int r = 0; r < 4; ++r) {
      float invr = __shfl(rinv[qs], lg * 4 + r);
      int row = qs * 16 + lg * 4 + r;
      osm[row * 264 + h * 32 + lr]      = o[qs][0][r] * invr;
      osm[row * 264 + h * 32 + 16 + lr] = o[qs][1][r] * invr;
    }
  __syncthreads();

  {
    int row = t >> 4;               // 32 rows x 16 threads
    int c16 = (t & 15) * 16;
    float vv[16]; float sm = 0.f, sq2 = 0.f;
#pragma unroll
    for (int j4 = 0; j4 < 4; ++j4) {
      float4 v4 = *reinterpret_cast<const float4*>(osm + row * 264 + c16 + j4 * 4);
      vv[j4 * 4 + 0] = v4.x; vv[j4 * 4 + 1] = v4.y;
      vv[j4 * 4 + 2] = v4.z; vv[j4 * 4 + 3] = v4.w;
      sm += v4.x + v4.y + v4.z + v4.w;
      sq2 += v4.x * v4.x + v4.y * v4.y + v4.z * v4.z + v4.w * v4.w;
    }
#pragma unroll
    for (int mm = 1; mm < 16; mm <<= 1) { sm += __shfl_xor(sm, mm); sq2 += __shfl_xor(sq2, mm); }
    float mean = sm * (1.f / 256.f);
    float var  = sq2 * (1.f / 256.f) - mean * mean;
    float rstd = rsqrtf(var + 1e-5f);
#pragma unroll
    for (int j4 = 0; j4 < 4; ++j4) {
      float4 g = *reinterpret_cast<const float4*>(gamma + c16 + j4 * 4);
      float4 b = *reinterpret_cast<const float4*>(beta + c16 + j4 * 4);
      ushort4 pk;
      pk.x = bfbits((vv[j4 * 4 + 0] - mean) * rstd * g.x + b.x);
      pk.y = bfbits((vv[j4 * 4 + 1] - mean) * rstd * g.y + b.y);
      pk.z = bfbits((vv[j4 * 4 + 2] - mean) * rstd * g.z + b.z);
      pk.w = bfbits((vv[j4 * 4 + 3] - mean) * rstd * g.w + b.w);
      *reinterpret_cast<ushort4*>(&ansm[row * 264 + c16 + j4 * 4]) = pk;
    }
  }
  __syncthreads();

#pragma unroll
  for (int qs = 0; qs < 2; ++qs) {
    f4v acc2[2];
    acc2[0] = f4v{0.f, 0.f, 0.f, 0.f}; acc2[1] = f4v{0.f, 0.f, 0.f, 0.f};
#pragma unroll
    for (int k0 = 0; k0 < 256; k0 += 32) {
      bf8v afr = *reinterpret_cast<const bf8v*>(&ansm[(qs * 16 + lr) * 264 + lg * 8 + k0]);
#pragma unroll
      for (int nt = 0; nt < 2; ++nt) {
        bf8v bfrg = *reinterpret_cast<const bf8v*>(
            wob + (long)(h * 32 + nt * 16 + lr) * 256 + lg * 8 + k0);
        acc2[nt] = mfma16(afr, bfrg, acc2[nt]);
      }
    }
#pragma unroll
    for (int nt = 0; nt < 2; ++nt) {
      int ocol = h * 32 + nt * 16 + lr;
      float bov = bo[ocol];
#pragma unroll
      for (int r = 0; r < 4; ++r) {
        int orow = q0 + qs * 16 + lg * 4 + r;
        outp[(bS + orow) * 256 + ocol] = acc2[nt][r] + bov;
      }
    }
  }
}

// ---------------------------------------------------------------- launch
extern "C" void kernel_launch(void* const* d_in, const int* in_sizes, int n_in,
                              void* d_out, int out_size, void* d_ws, size_t ws_size,
                              hipStream_t stream) {
  const float* q   = (const float*)d_in[0];
  const int*   km  = (const int*)d_in[1];
  const float* bias = (const float*)d_in[2];
  const float* Wq = (const float*)d_in[3];
  const float* bq = (const float*)d_in[4];
  const float* Wk = (const float*)d_in[5];
  const float* bk = (const float*)d_in[6];
  const float* Wv = (const float*)d_in[7];
  const float* bv = (const float*)d_in[8];
  const float* gamma = (const float*)d_in[9];
  const float* beta  = (const float*)d_in[10];
  const float* Wo = (const float*)d_in[11];
  const float* bo = (const float*)d_in[12];

  char* wsb = (char*)d_ws;
  __hip_bfloat16* q_bf = (__hip_bfloat16*)(wsb + 0);
  __hip_bfloat16* qh   = (__hip_bfloat16*)(wsb + (4  << 20));
  __hip_bfloat16* kh   = (__hip_bfloat16*)(wsb + (8  << 20));
  __hip_bfloat16* vt   = (__hip_bfloat16*)(wsb + (12 << 20));
  __hip_bfloat16* wbf  = (__hip_bfloat16*)(wsb + (16 << 20));
  float*          mskf = (float*)         (wsb + (17 << 20));
  unsigned*       cnt  = (unsigned*)      (wsb + (17 << 20) + 32768);
  __hip_bfloat16* wob  = wbf + 196608;

  prep_kernel<<<2305, 256, 0, stream>>>(q, Wq, Wk, Wv, Wo, km, q_bf, wbf, mskf, cnt);
  qkv_gemm<<<dim3(128, 2, 3), 256, 0, stream>>>(q_bf, wbf, bq, bk, bv, qh, kh, vt);
  attn_kernel<<<256, 512, 0, stream>>>(qh, kh, vt, bias, mskf, wob,
                                       gamma, beta, bo, cnt, (float*)d_out);
}

// Round 13
// 203.802 us; speedup vs baseline: 1.5354x; 1.5354x over previous
//
#include <hip/hip_runtime.h>
#include <hip/hip_bf16.h>

// Problem: B=8, S=1024, D=256, H=8, HD=32
// Pipeline (3 kernels):
//   prep:      q,Wq,Wk,Wv,Wo f32 -> bf16; kv_mask -> additive f32; zero sync cnt
//   qkv_gemm:  z=0: qh=(q@Wq^T+bq)*SCL, z=1: kh=q@Wk^T+bk, z=2: vt=Wv@q^T+bv (V^T)
//   attn:      flash attention, block=(b, 32-q-tile), wave=head w/ 2 q-subtiles.
//              Per-batch rendezvous every 2 k-tiles keeps sibling blocks
//              k-aligned so K/V stays cache-shared (R12 PROVED traffic fix:
//              FETCH 540->138 MB). R13: rendezvous atomics are RELAXED (R12's
//              ACQ_REL/ACQUIRE emitted L1-invalidate per poll -> 12us/sync,
//              3x regression). Counter is pacing-only: no data flows through
//              it, so relaxed is correct; bounded spin guard = no hang risk.
//              No online max; raw lgkm-only barriers; 2-deep bias prefetch.
//              Fused LayerNorm + @Wo^T+bo -> d_out (f32).
//
// Workspace: q_bf(4M) qh(4M@4M) kh(4M@8M) vt(4M@12M) w_bf(512K@16M)
//            mskf(32K@17M) cnt(32B @17M+32K)

static constexpr int SEQ = 1024;
static constexpr float SCL  = 0.17677669529663687f;  // 1/sqrt(32)
static constexpr float NEGV = -1000000000.0f;

typedef __attribute__((ext_vector_type(8))) __bf16 bf8v;
typedef __attribute__((ext_vector_type(4))) float  f4v;

__device__ __forceinline__ f4v mfma16(bf8v a, bf8v b, f4v c) {
  return __builtin_amdgcn_mfma_f32_16x16x32_bf16(a, b, c, 0, 0, 0);
}
__device__ __forceinline__ unsigned short bfbits(float f) {
  __hip_bfloat16 hbf = __float2bfloat16(f);
  unsigned short u; __builtin_memcpy(&u, &hbf, 2); return u;
}
__device__ __forceinline__ float bf2f(unsigned short u) {
  unsigned x = ((unsigned)u) << 16; float f; __builtin_memcpy(&f, &x, 4); return f;
}
// Barrier that does NOT drain outstanding global (vmcnt) loads.
__device__ __forceinline__ void lds_barrier() {
  __builtin_amdgcn_sched_barrier(0);
  asm volatile("s_waitcnt lgkmcnt(0)" ::: "memory");
  __builtin_amdgcn_s_barrier();
  __builtin_amdgcn_sched_barrier(0);
}

// ---------------------------------------------------------------- prep
__global__ __launch_bounds__(256) void prep_kernel(
    const float* __restrict__ q, const float* __restrict__ Wq,
    const float* __restrict__ Wk, const float* __restrict__ Wv,
    const float* __restrict__ Wo, const int* __restrict__ km,
    __hip_bfloat16* __restrict__ q_bf, __hip_bfloat16* __restrict__ w_bf,
    float* __restrict__ mskf, unsigned* __restrict__ cnt)
{
  const int NQ4 = (8192 * 256) / 4;
  const int NW4 = 65536 / 4;
  int t = threadIdx.x;

  if (blockIdx.x == 2304) {
    if (t < 8) cnt[t] = 0u;   // rendezvous counters (fresh each launch/replay)
    __shared__ int isbool;
    if (t == 0) isbool = 0;
    __syncthreads();
    const unsigned* u = (const unsigned*)km;
    int any = 0;
    for (int i = t; i < 2048; i += 256)
      if (u[i] & ~1u) any = 1;
    if (any) isbool = 1;   // benign race
    __syncthreads();
    const unsigned char* b8 = (const unsigned char*)km;
    for (int i = t; i < 8192; i += 256) {
      int mv = isbool ? (int)b8[i] : km[i];
      mskf[i] = mv ? 0.f : NEGV;
    }
    return;
  }

  int i = blockIdx.x * 256 + t;
  const float4* src; __hip_bfloat16* dst;
  if (i < NQ4) {
    src = (const float4*)q + i;
    dst = q_bf + (long)i * 4;
  } else {
    int j = i - NQ4; int w = j >> 14; int o4 = j & (NW4 - 1);
    const float* sp = (w == 0) ? Wq : (w == 1) ? Wk : (w == 2) ? Wv : Wo;
    src = (const float4*)sp + o4;
    dst = w_bf + w * 65536 + o4 * 4;
  }
  float4 v = *src;
  ushort4 pk;
  pk.x = bfbits(v.x); pk.y = bfbits(v.y); pk.z = bfbits(v.z); pk.w = bfbits(v.w);
  *reinterpret_cast<ushort4*>(dst) = pk;
}

// ------------------------------------------------- fused QKV GEMM (K=256)
__global__ __launch_bounds__(256) void qkv_gemm(
    const __hip_bfloat16* __restrict__ q_bf, const __hip_bfloat16* __restrict__ w_bf,
    const float* __restrict__ bq, const float* __restrict__ bk,
    const float* __restrict__ bv,
    __hip_bfloat16* __restrict__ qh, __hip_bfloat16* __restrict__ kh,
    __hip_bfloat16* __restrict__ vt)
{
  int z = blockIdx.z;
  int w = threadIdx.x >> 6;
  int l = threadIdx.x & 63, lr = l & 15, lg = l >> 4;

  const __hip_bfloat16 *A, *Bm; const float* bias; __hip_bfloat16* out;
  long ldOut; int m0, n0;
  if (z < 2) {
    A = q_bf; Bm = w_bf + z * 65536; bias = z ? bk : bq; out = z ? kh : qh;
    ldOut = 256;
    m0 = blockIdx.x * 64; n0 = blockIdx.y * 128 + w * 32;
  } else {
    A = w_bf + 2 * 65536; Bm = q_bf; bias = bv; out = vt; ldOut = 8192;
    int bid = blockIdx.y * 128 + blockIdx.x;
    m0 = (bid >> 6) * 64; n0 = (bid & 63) * 128 + w * 32;
  }

  f4v acc[4][2];
#pragma unroll
  for (int mt = 0; mt < 4; ++mt)
#pragma unroll
    for (int nt = 0; nt < 2; ++nt) acc[mt][nt] = f4v{0.f, 0.f, 0.f, 0.f};

  const __hip_bfloat16* Ab = A  + (long)(m0 + lr) * 256 + lg * 8;
  const __hip_bfloat16* Bb = Bm + (long)(n0 + lr) * 256 + lg * 8;
#pragma unroll
  for (int k0 = 0; k0 < 256; k0 += 32) {
    bf8v af[4], bfr[2];
#pragma unroll
    for (int mt = 0; mt < 4; ++mt)
      af[mt] = *reinterpret_cast<const bf8v*>(Ab + (long)mt * 16 * 256 + k0);
#pragma unroll
    for (int nt = 0; nt < 2; ++nt)
      bfr[nt] = *reinterpret_cast<const bf8v*>(Bb + (long)nt * 16 * 256 + k0);
#pragma unroll
    for (int mt = 0; mt < 4; ++mt)
#pragma unroll
      for (int nt = 0; nt < 2; ++nt)
        acc[mt][nt] = mfma16(af[mt], bfr[nt], acc[mt][nt]);
  }

#pragma unroll
  for (int mt = 0; mt < 4; ++mt) {
    int mrow = m0 + mt * 16 + lg * 4;
#pragma unroll
    for (int nt = 0; nt < 2; ++nt) {
      int ncol = n0 + nt * 16 + lr;
#pragma unroll
      for (int r = 0; r < 4; ++r) {
        float v = acc[mt][nt][r] + ((z == 2) ? bias[mrow + r] : bias[ncol]);
        if (z == 0) v *= SCL;   // fold 1/sqrt(HD) into Q projection
        out[(long)(mrow + r) * ldOut + ncol] = __float2bfloat16(v);
      }
    }
  }
}

// ---------------------------------------------------------------- attention
// grid = 256 (wgid = qt*8 + b), block = 512 (8 waves; wave = head, 32 q-rows
// as 2 subtiles). KT=32, raw barrier per tile, relaxed rendezvous per 2 tiles.
__global__ __launch_bounds__(512, 2) void attn_kernel(
    const __hip_bfloat16* __restrict__ qh, const __hip_bfloat16* __restrict__ kh,
    const __hip_bfloat16* __restrict__ vt, const float* __restrict__ bias,
    const float* __restrict__ mskf, const __hip_bfloat16* __restrict__ wob,
    const float* __restrict__ gamma, const float* __restrict__ beta,
    const float* __restrict__ bo, unsigned* __restrict__ cnt,
    float* __restrict__ outp)
{
  // loop:   bsm 2 x [32 q][8h x 36 + 4 pad = 292] bf16 = 37376 B
  //         psm [8w][16 q][40 k] bf16 = 10240 B @37376 ; msk 1024 f32 @47616
  // epilogue: osm f32 [32][264] = 33792 B @0 ; ansm bf16 [32][264] = 16896 B @33792
  __shared__ __align__(16) char smem[51712];
  __hip_bfloat16* bsm = (__hip_bfloat16*)smem;
  __hip_bfloat16* psm = (__hip_bfloat16*)(smem + 37376);
  float* msk = (float*)(smem + 47616);
  float* osm = (float*)smem;
  __hip_bfloat16* ansm = (__hip_bfloat16*)(smem + 33792);

  int bb = blockIdx.x & 7;           // XCD-affinity: batch -> XCD
  int qt = blockIdx.x >> 3;          // 0..31
  int h  = threadIdx.x >> 6;
  int l  = threadIdx.x & 63, lr = l & 15, lg = l >> 4;
  int q0 = qt * 32;
  long bS = (long)bb * SEQ;
  int t = threadIdx.x;
  // staging map: 32 rows x 16 threads; thread -> (q-row sq, k-quad kp, h-half hh)
  int sq = t >> 4, kp = (t >> 1) & 7, hh = t & 1;

  for (int i = t; i < 1024; i += 512) msk[i] = mskf[bS + i];

  bf8v qf[2];
#pragma unroll
  for (int qs = 0; qs < 2; ++qs)
    qf[qs] = *reinterpret_cast<const bf8v*>(
        qh + (bS + q0 + qs * 16 + lr) * 256 + h * 32 + lg * 8);

  f4v o[2][2];
  float lsum[2] = {0.f, 0.f};
#pragma unroll
  for (int qs = 0; qs < 2; ++qs)
#pragma unroll
    for (int nt = 0; nt < 2; ++nt) o[qs][nt] = f4v{0.f, 0.f, 0.f, 0.f};

  const float* bgb = bias + (bS + q0 + sq) * 8192L + 4 * hh;

  auto loadBias = [&](int tile, float4 (&br)[4]) {
    int kb = tile * 32;
#pragma unroll
    for (int kk = 0; kk < 4; ++kk)
      br[kk] = *reinterpret_cast<const float4*>(bgb + (long)(kb + 4 * kp + kk) * 8);
  };
  // (bias + mask) -> bf16 packed along k, layout [q][h][k]
  auto cvtWrite = [&](int buf, const float4 (&br)[4], int tile) {
    int kb = tile * 32;
    float mk[4];
#pragma unroll
    for (int kk = 0; kk < 4; ++kk) mk[kk] = msk[kb + 4 * kp + kk];
    __hip_bfloat16* bp = bsm + buf * 9344 + sq * 292 + 4 * kp;
    float w_[4][4] = {{br[0].x, br[0].y, br[0].z, br[0].w},
                      {br[1].x, br[1].y, br[1].z, br[1].w},
                      {br[2].x, br[2].y, br[2].z, br[2].w},
                      {br[3].x, br[3].y, br[3].z, br[3].w}};
#pragma unroll
    for (int i = 0; i < 4; ++i) {
      ushort4 hb;
      hb.x = bfbits(w_[0][i] + mk[0]); hb.y = bfbits(w_[1][i] + mk[1]);
      hb.z = bfbits(w_[2][i] + mk[2]); hb.w = bfbits(w_[3][i] + mk[3]);
      *reinterpret_cast<ushort4*>(bp + (4 * hh + i) * 36) = hb;
    }
  };
  auto loadKV = [&](int tile, bf8v (&kf)[2], bf8v (&vf)[2]) {
    int kbase = tile * 32;
#pragma unroll
    for (int nt = 0; nt < 2; ++nt)
      kf[nt] = *reinterpret_cast<const bf8v*>(
          kh + (bS + kbase + nt * 16 + lr) * 256 + h * 32 + lg * 8);
#pragma unroll
    for (int n2 = 0; n2 < 2; ++n2)
      vf[n2] = *reinterpret_cast<const bf8v*>(
          vt + (long)(h * 32 + n2 * 16 + lr) * 8192 + bS + kbase + lg * 8);
  };

  auto compute = [&](int kt, const bf8v (&kf)[2], const bf8v (&vf)[2]) {
    const __hip_bfloat16* bbp = bsm + (kt & 1) * 9344;
#pragma unroll
    for (int qs = 0; qs < 2; ++qs) {
      f4v z4 = f4v{0.f, 0.f, 0.f, 0.f};
      f4v s0 = mfma16(kf[0], qf[qs], z4);   // lane q = lr, k = 4lg+j
      f4v s1 = mfma16(kf[1], qf[qs], z4);   // k = 16 + 4lg+j

      const __hip_bfloat16* bp = bbp + (qs * 16 + lr) * 292 + h * 36;
      ushort4 b0 = *reinterpret_cast<const ushort4*>(bp + lg * 4);
      ushort4 b1 = *reinterpret_cast<const ushort4*>(bp + 16 + lg * 4);

      float p[8];
      p[0] = __expf(s0[0] + bf2f(b0.x)); p[1] = __expf(s0[1] + bf2f(b0.y));
      p[2] = __expf(s0[2] + bf2f(b0.z)); p[3] = __expf(s0[3] + bf2f(b0.w));
      p[4] = __expf(s1[0] + bf2f(b1.x)); p[5] = __expf(s1[1] + bf2f(b1.y));
      p[6] = __expf(s1[2] + bf2f(b1.z)); p[7] = __expf(s1[3] + bf2f(b1.w));
      lsum[qs] += ((p[0] + p[1]) + (p[2] + p[3])) + ((p[4] + p[5]) + (p[6] + p[7]));

      __hip_bfloat16* pw = psm + h * 640 + lr * 40;
      ushort4 pk0, pk1;
      pk0.x = bfbits(p[0]); pk0.y = bfbits(p[1]); pk0.z = bfbits(p[2]); pk0.w = bfbits(p[3]);
      pk1.x = bfbits(p[4]); pk1.y = bfbits(p[5]); pk1.z = bfbits(p[6]); pk1.w = bfbits(p[7]);
      *reinterpret_cast<ushort4*>(pw + 4 * lg)      = pk0;
      *reinterpret_cast<ushort4*>(pw + 16 + 4 * lg) = pk1;

      bf8v pa = *reinterpret_cast<const bf8v*>(psm + h * 640 + lr * 40 + lg * 8);
      o[qs][0] = mfma16(pa, vf[0], o[qs][0]);
      o[qs][1] = mfma16(pa, vf[1], o[qs][1]);
    }
  };

  // per-batch rendezvous, RELAXED atomics: pacing hint only (no data ordering
  // needed). R12's ACQUIRE spin emitted cache-invalidates per poll -> 3x
  // regression. Bounded guard: correctness never depends on alignment.
  auto rendezvous = [&](int phase) {
    if (t == 0) {
      __hip_atomic_fetch_add(cnt + bb, 1u, __ATOMIC_RELAXED,
                             __HIP_MEMORY_SCOPE_AGENT);
      unsigned tgt = 32u * (unsigned)(phase + 1);
      int guard = 0;
      while (__hip_atomic_load(cnt + bb, __ATOMIC_RELAXED,
                               __HIP_MEMORY_SCOPE_AGENT) < tgt &&
             ++guard < 200000)
        __builtin_amdgcn_s_sleep(2);
    }
    __builtin_amdgcn_sched_barrier(0);
    __builtin_amdgcn_s_barrier();
    __builtin_amdgcn_sched_barrier(0);
  };

  float4 brA[4], brB[4];
  bf8v kfA[2], vfA[2], kfB[2], vfB[2];

  loadBias(0, brA);
  loadBias(1, brB);
  loadKV(0, kfA, vfA);
  lds_barrier();              // msk visible; prefetches stay in flight
  cvtWrite(0, brA, 0);        // one-time wait on brA
  lds_barrier();

  for (int m = 0; m < 16; ++m) {
    rendezvous(m);
    { int kt = 2 * m;                       // compute even tile from bsm buf0
      if (kt + 2 < 32) loadBias(kt + 2, brA);
      loadKV(kt + 1, kfB, vfB);
      compute(kt, kfA, vfA);
      cvtWrite(1, brB, kt + 1);
      lds_barrier(); }
    { int kt = 2 * m + 1;                   // compute odd tile from bsm buf1
      if (kt + 2 < 32) { loadBias(kt + 2, brB); loadKV(kt + 1, kfA, vfA); }
      compute(kt, kfB, vfB);
      if (kt + 1 < 32) cvtWrite(0, brA, kt + 1);
      lds_barrier(); }
  }

  // ---- epilogue: lsum reduce, stage normalized O, LayerNorm, out-projection ----
  float rinv[2];
#pragma unroll
  for (int qs = 0; qs < 2; ++qs) {
    float s = lsum[qs];
    s += __shfl_xor(s, 16);
    s += __shfl_xor(s, 32);
    rinv[qs] = 1.f / s;
  }

  __syncthreads();   // all waves done with bsm/psm before osm aliases them
#pragma unroll
  for (int qs = 0; qs < 2; ++qs)
#pragma unroll
    for (int r = 0; r < 4; ++r) {
      float invr = __shfl(rinv[qs], lg * 4 + r);
      int row = qs * 16 + lg * 4 + r;
      osm[row * 264 + h * 32 + lr]      = o[qs][0][r] * invr;
      osm[row * 264 + h * 32 + 16 + lr] = o[qs][1][r] * invr;
    }
  __syncthreads();

  {
    int row = t >> 4;               // 32 rows x 16 threads
    int c16 = (t & 15) * 16;
    float vv[16]; float sm = 0.f, sq2 = 0.f;
#pragma unroll
    for (int j4 = 0; j4 < 4; ++j4) {
      float4 v4 = *reinterpret_cast<const float4*>(osm + row * 264 + c16 + j4 * 4);
      vv[j4 * 4 + 0] = v4.x; vv[j4 * 4 + 1] = v4.y;
      vv[j4 * 4 + 2] = v4.z; vv[j4 * 4 + 3] = v4.w;
      sm += v4.x + v4.y + v4.z + v4.w;
      sq2 += v4.x * v4.x + v4.y * v4.y + v4.z * v4.z + v4.w * v4.w;
    }
#pragma unroll
    for (int mm = 1; mm < 16; mm <<= 1) { sm += __shfl_xor(sm, mm); sq2 += __shfl_xor(sq2, mm); }
    float mean = sm * (1.f / 256.f);
    float var  = sq2 * (1.f / 256.f) - mean * mean;
    float rstd = rsqrtf(var + 1e-5f);
#pragma unroll
    for (int j4 = 0; j4 < 4; ++j4) {
      float4 g = *reinterpret_cast<const float4*>(gamma + c16 + j4 * 4);
      float4 b = *reinterpret_cast<const float4*>(beta + c16 + j4 * 4);
      ushort4 pk;
      pk.x = bfbits((vv[j4 * 4 + 0] - mean) * rstd * g.x + b.x);
      pk.y = bfbits((vv[j4 * 4 + 1] - mean) * rstd * g.y + b.y);
      pk.z = bfbits((vv[j4 * 4 + 2] - mean) * rstd * g.z + b.z);
      pk.w = bfbits((vv[j4 * 4 + 3] - mean) * rstd * g.w + b.w);
      *reinterpret_cast<ushort4*>(&ansm[row * 264 + c16 + j4 * 4]) = pk;
    }
  }
  __syncthreads();

#pragma unroll
  for (int qs = 0; qs < 2; ++qs) {
    f4v acc2[2];
    acc2[0] = f4v{0.f, 0.f, 0.f, 0.f}; acc2[1] = f4v{0.f, 0.f, 0.f, 0.f};
#pragma unroll
    for (int k0 = 0; k0 < 256; k0 += 32) {
      bf8v afr = *reinterpret_cast<const bf8v*>(&ansm[(qs * 16 + lr) * 264 + lg * 8 + k0]);
#pragma unroll
      for (int nt = 0; nt < 2; ++nt) {
        bf8v bfrg = *reinterpret_cast<const bf8v*>(
            wob + (long)(h * 32 + nt * 16 + lr) * 256 + lg * 8 + k0);
        acc2[nt] = mfma16(afr, bfrg, acc2[nt]);
      }
    }
#pragma unroll
    for (int nt = 0; nt < 2; ++nt) {
      int ocol = h * 32 + nt * 16 + lr;
      float bov = bo[ocol];
#pragma unroll
      for (int r = 0; r < 4; ++r) {
        int orow = q0 + qs * 16 + lg * 4 + r;
        outp[(bS + orow) * 256 + ocol] = acc2[nt][r] + bov;
      }
    }
  }
}

// ---------------------------------------------------------------- launch
extern "C" void kernel_launch(void* const* d_in, const int* in_sizes, int n_in,
                              void* d_out, int out_size, void* d_ws, size_t ws_size,
                              hipStream_t stream) {
  const float* q   = (const float*)d_in[0];
  const int*   km  = (const int*)d_in[1];
  const float* bias = (const float*)d_in[2];
  const float* Wq = (const float*)d_in[3];
  const float* bq = (const float*)d_in[4];
  const float* Wk = (const float*)d_in[5];
  const float* bk = (const float*)d_in[6];
  const float* Wv = (const float*)d_in[7];
  const float* bv = (const float*)d_in[8];
  const float* gamma = (const float*)d_in[9];
  const float* beta  = (const float*)d_in[10];
  const float* Wo = (const float*)d_in[11];
  const float* bo = (const float*)d_in[12];

  char* wsb = (char*)d_ws;
  __hip_bfloat16* q_bf = (__hip_bfloat16*)(wsb + 0);
  __hip_bfloat16* qh   = (__hip_bfloat16*)(wsb + (4  << 20));
  __hip_bfloat16* kh   = (__hip_bfloat16*)(wsb + (8  << 20));
  __hip_bfloat16* vt   = (__hip_bfloat16*)(wsb + (12 << 20));
  __hip_bfloat16* wbf  = (__hip_bfloat16*)(wsb + (16 << 20));
  float*          mskf = (float*)         (wsb + (17 << 20));
  unsigned*       cnt  = (unsigned*)      (wsb + (17 << 20) + 32768);
  __hip_bfloat16* wob  = wbf + 196608;

  prep_kernel<<<2305, 256, 0, stream>>>(q, Wq, Wk, Wv, Wo, km, q_bf, wbf, mskf, cnt);
  qkv_gemm<<<dim3(128, 2, 3), 256, 0, stream>>>(q_bf, wbf, bq, bk, bv, qh, kh, vt);
  attn_kernel<<<256, 512, 0, stream>>>(qh, kh, vt, bias, mskf, wob,
                                       gamma, beta, bo, cnt, (float*)d_out);
}

// Round 14
// 126.414 us; speedup vs baseline: 2.4753x; 1.6122x over previous
//
#include <hip/hip_runtime.h>
#include <hip/hip_bf16.h>

// Problem: B=8, S=1024, D=256, H=8, HD=32
// Pipeline (3 kernels):
//   prep:      q,Wq,Wk,Wv,Wo f32 -> bf16; kv_mask (int32/bool auto) -> additive f32
//   qkv_gemm:  z=0: qh=(q@Wq^T+bq)*SCL, z=1: kh=q@Wk^T+bk, z=2: vt=Wv@q^T+bv (V^T)
//   attn:      flash attention, block=(b, 32-q-tile), wave=head w/ 2 q-subtiles.
//              R14 = R11 (best, 114.2us) with KT=64: 16 phases instead of 32 ->
//              half the k-loop barriers and per-phase bookkeeping. R11 grid
//              (256 = 1 block/CU) means occupancy is 8 waves/CU regardless, so
//              launch_bounds(512,2) gives 256-VGPR budget (R6's KT=64 failure
//              was the 128-cap spills). Rendezvous REMOVED (R12/R13: traffic
//              fix proven, sync cost 90us straggler chaining - net loss).
//              No online max; raw lgkm-only barriers; 2-deep bias prefetch.
//              Fused LayerNorm + @Wo^T+bo -> d_out (f32).
//
// Workspace: q_bf(4M) qh(4M@4M) kh(4M@8M) vt(4M@12M) w_bf(512K@16M) mskf(32K@17M)

static constexpr int SEQ = 1024;
static constexpr float SCL  = 0.17677669529663687f;  // 1/sqrt(32)
static constexpr float NEGV = -1000000000.0f;

typedef __attribute__((ext_vector_type(8))) __bf16 bf8v;
typedef __attribute__((ext_vector_type(4))) float  f4v;

__device__ __forceinline__ f4v mfma16(bf8v a, bf8v b, f4v c) {
  return __builtin_amdgcn_mfma_f32_16x16x32_bf16(a, b, c, 0, 0, 0);
}
__device__ __forceinline__ unsigned short bfbits(float f) {
  __hip_bfloat16 hbf = __float2bfloat16(f);
  unsigned short u; __builtin_memcpy(&u, &hbf, 2); return u;
}
__device__ __forceinline__ float bf2f(unsigned short u) {
  unsigned x = ((unsigned)u) << 16; float f; __builtin_memcpy(&f, &x, 4); return f;
}
// Barrier that does NOT drain outstanding global (vmcnt) loads.
__device__ __forceinline__ void lds_barrier() {
  __builtin_amdgcn_sched_barrier(0);
  asm volatile("s_waitcnt lgkmcnt(0)" ::: "memory");
  __builtin_amdgcn_s_barrier();
  __builtin_amdgcn_sched_barrier(0);
}

// ---------------------------------------------------------------- prep
__global__ __launch_bounds__(256) void prep_kernel(
    const float* __restrict__ q, const float* __restrict__ Wq,
    const float* __restrict__ Wk, const float* __restrict__ Wv,
    const float* __restrict__ Wo, const int* __restrict__ km,
    __hip_bfloat16* __restrict__ q_bf, __hip_bfloat16* __restrict__ w_bf,
    float* __restrict__ mskf)
{
  const int NQ4 = (8192 * 256) / 4;
  const int NW4 = 65536 / 4;
  int t = threadIdx.x;

  if (blockIdx.x == 2304) {
    __shared__ int isbool;
    if (t == 0) isbool = 0;
    __syncthreads();
    const unsigned* u = (const unsigned*)km;
    int any = 0;
    for (int i = t; i < 2048; i += 256)
      if (u[i] & ~1u) any = 1;
    if (any) isbool = 1;   // benign race
    __syncthreads();
    const unsigned char* b8 = (const unsigned char*)km;
    for (int i = t; i < 8192; i += 256) {
      int mv = isbool ? (int)b8[i] : km[i];
      mskf[i] = mv ? 0.f : NEGV;
    }
    return;
  }

  int i = blockIdx.x * 256 + t;
  const float4* src; __hip_bfloat16* dst;
  if (i < NQ4) {
    src = (const float4*)q + i;
    dst = q_bf + (long)i * 4;
  } else {
    int j = i - NQ4; int w = j >> 14; int o4 = j & (NW4 - 1);
    const float* sp = (w == 0) ? Wq : (w == 1) ? Wk : (w == 2) ? Wv : Wo;
    src = (const float4*)sp + o4;
    dst = w_bf + w * 65536 + o4 * 4;
  }
  float4 v = *src;
  ushort4 pk;
  pk.x = bfbits(v.x); pk.y = bfbits(v.y); pk.z = bfbits(v.z); pk.w = bfbits(v.w);
  *reinterpret_cast<ushort4*>(dst) = pk;
}

// ------------------------------------------------- fused QKV GEMM (K=256)
__global__ __launch_bounds__(256) void qkv_gemm(
    const __hip_bfloat16* __restrict__ q_bf, const __hip_bfloat16* __restrict__ w_bf,
    const float* __restrict__ bq, const float* __restrict__ bk,
    const float* __restrict__ bv,
    __hip_bfloat16* __restrict__ qh, __hip_bfloat16* __restrict__ kh,
    __hip_bfloat16* __restrict__ vt)
{
  int z = blockIdx.z;
  int w = threadIdx.x >> 6;
  int l = threadIdx.x & 63, lr = l & 15, lg = l >> 4;

  const __hip_bfloat16 *A, *Bm; const float* bias; __hip_bfloat16* out;
  long ldOut; int m0, n0;
  if (z < 2) {
    A = q_bf; Bm = w_bf + z * 65536; bias = z ? bk : bq; out = z ? kh : qh;
    ldOut = 256;
    m0 = blockIdx.x * 64; n0 = blockIdx.y * 128 + w * 32;
  } else {
    A = w_bf + 2 * 65536; Bm = q_bf; bias = bv; out = vt; ldOut = 8192;
    int bid = blockIdx.y * 128 + blockIdx.x;
    m0 = (bid >> 6) * 64; n0 = (bid & 63) * 128 + w * 32;
  }

  f4v acc[4][2];
#pragma unroll
  for (int mt = 0; mt < 4; ++mt)
#pragma unroll
    for (int nt = 0; nt < 2; ++nt) acc[mt][nt] = f4v{0.f, 0.f, 0.f, 0.f};

  const __hip_bfloat16* Ab = A  + (long)(m0 + lr) * 256 + lg * 8;
  const __hip_bfloat16* Bb = Bm + (long)(n0 + lr) * 256 + lg * 8;
#pragma unroll
  for (int k0 = 0; k0 < 256; k0 += 32) {
    bf8v af[4], bfr[2];
#pragma unroll
    for (int mt = 0; mt < 4; ++mt)
      af[mt] = *reinterpret_cast<const bf8v*>(Ab + (long)mt * 16 * 256 + k0);
#pragma unroll
    for (int nt = 0; nt < 2; ++nt)
      bfr[nt] = *reinterpret_cast<const bf8v*>(Bb + (long)nt * 16 * 256 + k0);
#pragma unroll
    for (int mt = 0; mt < 4; ++mt)
#pragma unroll
      for (int nt = 0; nt < 2; ++nt)
        acc[mt][nt] = mfma16(af[mt], bfr[nt], acc[mt][nt]);
  }

#pragma unroll
  for (int mt = 0; mt < 4; ++mt) {
    int mrow = m0 + mt * 16 + lg * 4;
#pragma unroll
    for (int nt = 0; nt < 2; ++nt) {
      int ncol = n0 + nt * 16 + lr;
#pragma unroll
      for (int r = 0; r < 4; ++r) {
        float v = acc[mt][nt][r] + ((z == 2) ? bias[mrow + r] : bias[ncol]);
        if (z == 0) v *= SCL;   // fold 1/sqrt(HD) into Q projection
        out[(long)(mrow + r) * ldOut + ncol] = __float2bfloat16(v);
      }
    }
  }
}

// ---------------------------------------------------------------- attention
// grid = 256 (wgid = qt*8 + b), block = 512 (8 waves; wave = head, 32 q-rows
// as 2 subtiles). KT=64 (16 phases), one raw barrier per phase.
__global__ __launch_bounds__(512, 2) void attn_kernel(
    const __hip_bfloat16* __restrict__ qh, const __hip_bfloat16* __restrict__ kh,
    const __hip_bfloat16* __restrict__ vt, const float* __restrict__ bias,
    const float* __restrict__ mskf, const __hip_bfloat16* __restrict__ wob,
    const float* __restrict__ gamma, const float* __restrict__ beta,
    const float* __restrict__ bo, float* __restrict__ outp)
{
  // loop:   bsm 2 x [32 q][8h x 68 + 4 pad = 548] bf16 (q-stride 1096 B) = 70144 B
  //         psm [8w][16 q][72 k] bf16 = 18432 B @70144 ; msk 1024 f32 @88576
  // epilogue: osm f32 [32][264] = 33792 B @0 ; ansm bf16 [32][264] @33792 (aliases bsm)
  __shared__ __align__(16) char smem[92672];
  __hip_bfloat16* bsm = (__hip_bfloat16*)smem;
  __hip_bfloat16* psm = (__hip_bfloat16*)(smem + 70144);
  float* msk = (float*)(smem + 88576);
  float* osm = (float*)smem;
  __hip_bfloat16* ansm = (__hip_bfloat16*)(smem + 33792);

  int bb = blockIdx.x & 7;           // XCD-affinity: batch -> XCD
  int qt = blockIdx.x >> 3;          // 0..31
  int h  = threadIdx.x >> 6;
  int l  = threadIdx.x & 63, lr = l & 15, lg = l >> 4;
  int q0 = qt * 32;
  long bS = (long)bb * SEQ;
  int t = threadIdx.x;
  // staging map: 32 rows x 16 threads; thread -> (q-row sq, k-oct kp, h-half hh)
  int sq = t >> 4, kp = (t >> 1) & 7, hh = t & 1;

  for (int i = t; i < 1024; i += 512) msk[i] = mskf[bS + i];

  bf8v qf[2];
#pragma unroll
  for (int qs = 0; qs < 2; ++qs)
    qf[qs] = *reinterpret_cast<const bf8v*>(
        qh + (bS + q0 + qs * 16 + lr) * 256 + h * 32 + lg * 8);

  f4v o[2][2];
  float lsum[2] = {0.f, 0.f};
#pragma unroll
  for (int qs = 0; qs < 2; ++qs)
#pragma unroll
    for (int nt = 0; nt < 2; ++nt) o[qs][nt] = f4v{0.f, 0.f, 0.f, 0.f};

  const float* bgb = bias + (bS + q0 + sq) * 8192L + 4 * hh;

  // phase = 64 k. thread loads 8 float4: k = kb + 8*kp + kk, h-half hh.
  auto loadBias = [&](int phase, float4 (&br)[8]) {
    int kb = phase * 64;
#pragma unroll
    for (int kk = 0; kk < 8; ++kk)
      br[kk] = *reinterpret_cast<const float4*>(bgb + (long)(kb + 8 * kp + kk) * 8);
  };
  // (bias + mask) -> bf16, layout [q][h][k], k-run of 8 -> b128 writes
  auto cvtWrite = [&](int buf, const float4 (&br)[8], int phase) {
    int kb = phase * 64;
    float mk[8];
#pragma unroll
    for (int kk = 0; kk < 8; ++kk) mk[kk] = msk[kb + 8 * kp + kk];
    __hip_bfloat16* bp = bsm + buf * 17536 + sq * 548 + 8 * kp;
#pragma unroll
    for (int i = 0; i < 4; ++i) {
      unsigned short w8[8];
#pragma unroll
      for (int kk = 0; kk < 8; ++kk) {
        float vv = (i == 0) ? br[kk].x : (i == 1) ? br[kk].y
                 : (i == 2) ? br[kk].z : br[kk].w;
        w8[kk] = bfbits(vv + mk[kk]);
      }
      __builtin_memcpy(bp + (4 * hh + i) * 68, w8, 16);   // b128 store
    }
  };
  auto loadKV = [&](int phase, bf8v (&kf)[4], bf8v (&vf)[2][2]) {
    int kbase = phase * 64;
#pragma unroll
    for (int u = 0; u < 4; ++u)
      kf[u] = *reinterpret_cast<const bf8v*>(
          kh + (bS + kbase + u * 16 + lr) * 256 + h * 32 + lg * 8);
#pragma unroll
    for (int n2 = 0; n2 < 2; ++n2)
#pragma unroll
      for (int s2 = 0; s2 < 2; ++s2)
        vf[n2][s2] = *reinterpret_cast<const bf8v*>(
            vt + (long)(h * 32 + n2 * 16 + lr) * 8192 + bS + kbase + s2 * 32 + lg * 8);
  };

  auto compute = [&](int phase, const bf8v (&kf)[4], const bf8v (&vf)[2][2]) {
    const __hip_bfloat16* bbp = bsm + (phase & 1) * 17536;
#pragma unroll
    for (int qs = 0; qs < 2; ++qs) {
      f4v z4 = f4v{0.f, 0.f, 0.f, 0.f};
      f4v s[4];
#pragma unroll
      for (int u = 0; u < 4; ++u) s[u] = mfma16(kf[u], qf[qs], z4);  // q=lr, k=16u+4lg+j

      const __hip_bfloat16* bp = bbp + (qs * 16 + lr) * 548 + h * 68;
      float v[16];
#pragma unroll
      for (int u = 0; u < 4; ++u) {
        ushort4 b4 = *reinterpret_cast<const ushort4*>(bp + u * 16 + lg * 4);
        v[u * 4 + 0] = s[u][0] + bf2f(b4.x);
        v[u * 4 + 1] = s[u][1] + bf2f(b4.y);
        v[u * 4 + 2] = s[u][2] + bf2f(b4.z);
        v[u * 4 + 3] = s[u][3] + bf2f(b4.w);
      }

      float p[16]; float ts = 0.f;
#pragma unroll
      for (int i = 0; i < 16; ++i) { p[i] = __expf(v[i]); ts += p[i]; }
      lsum[qs] += ts;

      __hip_bfloat16* pw = psm + h * 1152 + lr * 72;
#pragma unroll
      for (int u = 0; u < 4; ++u) {
        ushort4 pk;
        pk.x = bfbits(p[u * 4 + 0]); pk.y = bfbits(p[u * 4 + 1]);
        pk.z = bfbits(p[u * 4 + 2]); pk.w = bfbits(p[u * 4 + 3]);
        *reinterpret_cast<ushort4*>(pw + u * 16 + lg * 4) = pk;
      }

#pragma unroll
      for (int s2 = 0; s2 < 2; ++s2) {
        bf8v pa = *reinterpret_cast<const bf8v*>(psm + h * 1152 + lr * 72 + s2 * 32 + lg * 8);
        o[qs][0] = mfma16(pa, vf[0][s2], o[qs][0]);
        o[qs][1] = mfma16(pa, vf[1][s2], o[qs][1]);
      }
    }
  };

  float4 brA[8], brB[8];
  bf8v kf[4], vf[2][2];

  loadBias(0, brA);
  loadBias(1, brB);
  lds_barrier();              // msk visible; bias prefetches stay in flight
  cvtWrite(0, brA, 0);        // one-time wait on brA only
  lds_barrier();

  // 2-deep: phase p issues bias(p+2), computes p, LDS-writes bias(p+1).
  for (int m = 0; m < 8; ++m) {
    { int p = 2 * m;                        // compute from bsm buf0
      if (p + 2 < 16) loadBias(p + 2, brA);
      loadKV(p, kf, vf);
      compute(p, kf, vf);
      cvtWrite(1, brB, p + 1);
      lds_barrier(); }
    { int p = 2 * m + 1;                    // compute from bsm buf1
      if (p + 2 < 16) loadBias(p + 2, brB);
      loadKV(p, kf, vf);
      compute(p, kf, vf);
      if (p + 1 < 16) cvtWrite(0, brA, p + 1);
      lds_barrier(); }
  }

  // ---- epilogue: lsum reduce, stage normalized O, LayerNorm, out-projection ----
  float rinv[2];
#pragma unroll
  for (int qs = 0; qs < 2; ++qs) {
    float s = lsum[qs];
    s += __shfl_xor(s, 16);
    s += __shfl_xor(s, 32);
    rinv[qs] = 1.f / s;
  }

  __syncthreads();   // all waves done with bsm/psm before osm aliases them
#pragma unroll
  for (int qs = 0; qs < 2; ++qs)
#pragma unroll
    for (int r = 0; r < 4; ++r) {
      float invr = __shfl(rinv[qs], lg * 4 + r);
      int row = qs * 16 + lg * 4 + r;
      osm[row * 264 + h * 32 + lr]      = o[qs][0][r] * invr;
      osm[row * 264 + h * 32 + 16 + lr] = o[qs][1][r] * invr;
    }
  __syncthreads();

  {
    int row = t >> 4;               // 32 rows x 16 threads
    int c16 = (t & 15) * 16;
    float vv[16]; float sm = 0.f, sq2 = 0.f;
#pragma unroll
    for (int j4 = 0; j4 < 4; ++j4) {
      float4 v4 = *reinterpret_cast<const float4*>(osm + row * 264 + c16 + j4 * 4);
      vv[j4 * 4 + 0] = v4.x; vv[j4 * 4 + 1] = v4.y;
      vv[j4 * 4 + 2] = v4.z; vv[j4 * 4 + 3] = v4.w;
      sm += v4.x + v4.y + v4.z + v4.w;
      sq2 += v4.x * v4.x + v4.y * v4.y + v4.z * v4.z + v4.w * v4.w;
    }
#pragma unroll
    for (int mm = 1; mm < 16; mm <<= 1) { sm += __shfl_xor(sm, mm); sq2 += __shfl_xor(sq2, mm); }
    float mean = sm * (1.f / 256.f);
    float var  = sq2 * (1.f / 256.f) - mean * mean;
    float rstd = rsqrtf(var + 1e-5f);
#pragma unroll
    for (int j4 = 0; j4 < 4; ++j4) {
      float4 g = *reinterpret_cast<const float4*>(gamma + c16 + j4 * 4);
      float4 b = *reinterpret_cast<const float4*>(beta + c16 + j4 * 4);
      ushort4 pk;
      pk.x = bfbits((vv[j4 * 4 + 0] - mean) * rstd * g.x + b.x);
      pk.y = bfbits((vv[j4 * 4 + 1] - mean) * rstd * g.y + b.y);
      pk.z = bfbits((vv[j4 * 4 + 2] - mean) * rstd * g.z + b.z);
      pk.w = bfbits((vv[j4 * 4 + 3] - mean) * rstd * g.w + b.w);
      *reinterpret_cast<ushort4*>(&ansm[row * 264 + c16 + j4 * 4]) = pk;
    }
  }
  __syncthreads();

#pragma unroll
  for (int qs = 0; qs < 2; ++qs) {
    f4v acc2[2];
    acc2[0] = f4v{0.f, 0.f, 0.f, 0.f}; acc2[1] = f4v{0.f, 0.f, 0.f, 0.f};
#pragma unroll
    for (int k0 = 0; k0 < 256; k0 += 32) {
      bf8v afr = *reinterpret_cast<const bf8v*>(&ansm[(qs * 16 + lr) * 264 + lg * 8 + k0]);
#pragma unroll
      for (int nt = 0; nt < 2; ++nt) {
        bf8v bfrg = *reinterpret_cast<const bf8v*>(
            wob + (long)(h * 32 + nt * 16 + lr) * 256 + lg * 8 + k0);
        acc2[nt] = mfma16(afr, bfrg, acc2[nt]);
      }
    }
#pragma unroll
    for (int nt = 0; nt < 2; ++nt) {
      int ocol = h * 32 + nt * 16 + lr;
      float bov = bo[ocol];
#pragma unroll
      for (int r = 0; r < 4; ++r) {
        int orow = q0 + qs * 16 + lg * 4 + r;
        outp[(bS + orow) * 256 + ocol] = acc2[nt][r] + bov;
      }
    }
  }
}

// ---------------------------------------------------------------- launch
extern "C" void kernel_launch(void* const* d_in, const int* in_sizes, int n_in,
                              void* d_out, int out_size, void* d_ws, size_t ws_size,
                              hipStream_t stream) {
  const float* q   = (const float*)d_in[0];
  const int*   km  = (const int*)d_in[1];
  const float* bias = (const float*)d_in[2];
  const float* Wq = (const float*)d_in[3];
  const float* bq = (const float*)d_in[4];
  const float* Wk = (const float*)d_in[5];
  const float* bk = (const float*)d_in[6];
  const float* Wv = (const float*)d_in[7];
  const float* bv = (const float*)d_in[8];
  const float* gamma = (const float*)d_in[9];
  const float* beta  = (const float*)d_in[10];
  const float* Wo = (const float*)d_in[11];
  const float* bo = (const float*)d_in[12];

  char* wsb = (char*)d_ws;
  __hip_bfloat16* q_bf = (__hip_bfloat16*)(wsb + 0);
  __hip_bfloat16* qh   = (__hip_bfloat16*)(wsb + (4  << 20));
  __hip_bfloat16* kh   = (__hip_bfloat16*)(wsb + (8  << 20));
  __hip_bfloat16* vt   = (__hip_bfloat16*)(wsb + (12 << 20));
  __hip_bfloat16* wbf  = (__hip_bfloat16*)(wsb + (16 << 20));
  float*          mskf = (float*)         (wsb + (17 << 20));
  __hip_bfloat16* wob  = wbf + 196608;

  prep_kernel<<<2305, 256, 0, stream>>>(q, Wq, Wk, Wv, Wo, km, q_bf, wbf, mskf);
  qkv_gemm<<<dim3(128, 2, 3), 256, 0, stream>>>(q_bf, wbf, bq, bk, bv, qh, kh, vt);
  attn_kernel<<<256, 512, 0, stream>>>(qh, kh, vt, bias, mskf, wob,
                                       gamma, beta, bo, (float*)d_out);
}